// Round 11
// baseline (164.287 us; speedup 1.0000x reference)
//
#include <hip/hip_runtime.h>
#include <math.h>

#define NH 8
#define NN 4096
#define FF 128
#define SEG 32
#define NSEG (NN / SEG)  // 128

typedef unsigned long long u64;

// kA: va_src[h] = W_h @ a_src[h], va_dst[h] = W_h @ a_dst[h].  (8 blocks)
__global__ __launch_bounds__(128) void kA_va(
    const float* __restrict__ w, const float* __restrict__ a_src,
    const float* __restrict__ a_dst, float* __restrict__ va_s,
    float* __restrict__ va_d) {
  __shared__ float as[FF], ad[FF];
  const int head = blockIdx.x, i = threadIdx.x;
  as[i] = a_src[head * FF + i];
  ad[i] = a_dst[head * FF + i];
  __syncthreads();
  const float4* wr = reinterpret_cast<const float4*>(w + (size_t)head * FF * FF +
                                                     (size_t)i * FF);
  float s = 0.f, d = 0.f;
  #pragma unroll 8
  for (int q = 0; q < 32; ++q) {
    float4 v = wr[q];
    s += v.x * as[q * 4] + v.y * as[q * 4 + 1] + v.z * as[q * 4 + 2] +
         v.w * as[q * 4 + 3];
    d += v.x * ad[q * 4] + v.y * ad[q * 4 + 1] + v.z * ad[q * 4 + 2] +
         v.w * ad[q * 4 + 3];
  }
  va_s[head * FF + i] = s;
  va_d[head * FF + i] = d;
}

// kB: scores attn_src[h,n] = h[n].va_s[h], attn_dst likewise. 32 rows/block.
__global__ __launch_bounds__(256) void kB_scores(
    const float* __restrict__ h, const float* __restrict__ va_s,
    const float* __restrict__ va_d, float* __restrict__ attn_src,
    float* __restrict__ attn_dst) {
  __shared__ float sh[32 * 132];          // h rows, padded stride
  __shared__ float vs[NH * 132], vd[NH * 132];
  const int r0 = blockIdx.x * 32;
  const int tid = threadIdx.x;
  const float4* hg = reinterpret_cast<const float4*>(h);
  #pragma unroll
  for (int it = 0; it < 4; ++it) {
    int q = tid + it * 256;
    int row = q >> 5, c4 = q & 31;
    float4 v = hg[(size_t)(r0 + row) * 32 + c4];
    float* dst = &sh[row * 132 + c4 * 4];
    dst[0] = v.x; dst[1] = v.y; dst[2] = v.z; dst[3] = v.w;
  }
  for (int q = tid; q < NH * FF; q += 256) {
    int hd = q >> 7, k = q & 127;
    vs[hd * 132 + k] = va_s[q];
    vd[hd * 132 + k] = va_d[q];
  }
  __syncthreads();
  const int row = tid >> 3, head = tid & 7;
  float s = 0.f, d = 0.f;
  const float* hr = &sh[row * 132];
  const float* vsp = &vs[head * 132];
  const float* vdp = &vd[head * 132];
  #pragma unroll 8
  for (int k = 0; k < FF; ++k) {
    float hv = hr[k];
    s += hv * vsp[k];
    d += hv * vdp[k];
  }
  attn_src[head * NN + r0 + row] = s;
  attn_dst[head * NN + r0 + row] = d;
}

// K2a: per (head, 512-chunk): bitonic sort of packed (sortkey32|idx) in LDS.
__global__ __launch_bounds__(256) void k2a_localsort(
    const float* __restrict__ adst, u64* __restrict__ runs) {
  __shared__ u64 sk[512];
  const int head = blockIdx.y, chunk = blockIdx.x, tid = threadIdx.x;
  const int base = head * NN + chunk * 512;
  for (int i = tid; i < 512; i += 256) {
    unsigned ub = __float_as_uint(adst[base + i]);
    unsigned u = (ub & 0x80000000u) ? ~ub : (ub | 0x80000000u);
    sk[i] = ((u64)u << 32) | (unsigned)(chunk * 512 + i);
  }
  __syncthreads();
  for (int k = 2; k <= 512; k <<= 1) {
    for (int j = k >> 1; j > 0; j >>= 1) {
      for (int t = tid; t < 512; t += 256) {
        int ixj = t ^ j;
        if (ixj > t) {
          u64 a = sk[t], b = sk[ixj];
          bool up = ((t & k) == 0);
          if (up ? (a > b) : (a < b)) { sk[t] = b; sk[ixj] = a; }
        }
      }
      __syncthreads();
    }
  }
  for (int i = tid; i < 512; i += 256) runs[base + i] = sk[i];
}

// K2m: merge-path merge of adjacent sorted runs of length L (4 outputs/thread).
template <int L, bool FINAL>
__global__ __launch_bounds__(256) void k2m(
    const u64* __restrict__ src, u64* __restrict__ dst,
    float* __restrict__ dsort, int* __restrict__ permd) {
  const int head = blockIdx.y;
  const int i = (blockIdx.x * 256 + threadIdx.x) * 4;
  const u64* S = src + head * NN;
  const int region = i / (2 * L), q0 = i % (2 * L);
  const u64* A = S + region * 2 * L;
  const u64* B = A + L;
  int lo = q0 > L ? q0 - L : 0, hi = q0 < L ? q0 : L;
  while (lo < hi) {
    int mid = (lo + hi) >> 1;
    if (A[mid] < B[q0 - 1 - mid]) lo = mid + 1; else hi = mid;
  }
  int a = lo, b = q0 - lo;
  #pragma unroll
  for (int t = 0; t < 4; ++t) {
    u64 va = a < L ? A[a] : ~0ULL;
    u64 vb = b < L ? B[b] : ~0ULL;
    u64 v;
    if (va < vb) { v = va; ++a; } else { v = vb; ++b; }
    const int q = region * 2 * L + q0 + t;
    if (FINAL) {
      unsigned u = (unsigned)(v >> 32);
      unsigned ub = (u & 0x80000000u) ? (u ^ 0x80000000u) : ~u;
      dsort[head * NN + q] = __uint_as_float(ub);
      permd[head * NN + q] = (int)(v & 0xffffffffu);
    } else {
      dst[head * NN + q] = v;
    }
  }
}

// kD: per (head, 32-row sorted tile): gather h[perm] rows (L2-resident),
// GEMM vs W_h (LDS chunk-staged), write hs in SORTED order (linear),
// and emit segment sums of e^{0.2d}.h' / e^{d}.h' + scalar z sums.
__global__ __launch_bounds__(256) void kD_gemm_seg(
    const float* __restrict__ h, const float* __restrict__ w,
    const float* __restrict__ dsort, const int* __restrict__ permd,
    float* __restrict__ hs, float* __restrict__ segs,
    float* __restrict__ segz) {
  __shared__ float sw[32 * 128];   // W k-chunk [32 k][128 o]
  __shared__ float hA[32 * 128];   // gathered h rows [row][k]
  __shared__ float red[2 * 8 * 128];
  __shared__ float se0[SEG], se1[SEG];
  __shared__ int sp[SEG];
  const int head = blockIdx.y, seg = blockIdx.x;
  const int tid = threadIdx.x;
  const int ty = tid >> 5, tx = tid & 31;
  if (tid < SEG) {
    float dv = dsort[head * NN + seg * SEG + tid];
    se0[tid] = expf(0.2f * dv);
    se1[tid] = expf(dv);
    sp[tid] = permd[head * NN + seg * SEG + tid];
  }
  __syncthreads();
  // gather 32 h rows into hA
  const float4* hg = reinterpret_cast<const float4*>(h);
  #pragma unroll
  for (int it = 0; it < 4; ++it) {
    int row = tid >> 3, c4 = (tid & 7) + it * 8;
    float4 v = hg[(size_t)sp[row] * 32 + c4];
    float* dst = &hA[row * 128 + c4 * 4];
    dst[0] = v.x; dst[1] = v.y; dst[2] = v.z; dst[3] = v.w;
  }
  float acc[4][4];
  #pragma unroll
  for (int i = 0; i < 4; ++i)
    #pragma unroll
    for (int j = 0; j < 4; ++j) acc[i][j] = 0.f;
  const float4* wg = reinterpret_cast<const float4*>(w + (size_t)head * FF * FF);
  for (int kc = 0; kc < 4; ++kc) {
    const int k0 = kc * 32;
    __syncthreads();
    #pragma unroll
    for (int it = 0; it < 4; ++it) {
      int q = tid + it * 256;
      int krow = q >> 5, c4 = q & 31;
      float4 v = wg[(size_t)(k0 + krow) * 32 + c4];
      float* dst = &sw[krow * 128 + c4 * 4];
      dst[0] = v.x; dst[1] = v.y; dst[2] = v.z; dst[3] = v.w;
    }
    __syncthreads();
    #pragma unroll 8
    for (int kk = 0; kk < 32; ++kk) {
      float4 b4 = *reinterpret_cast<const float4*>(&sw[kk * 128 + tx * 4]);
      #pragma unroll
      for (int ri = 0; ri < 4; ++ri) {
        float av = hA[(ty * 4 + ri) * 128 + k0 + kk];
        acc[ri][0] += av * b4.x;
        acc[ri][1] += av * b4.y;
        acc[ri][2] += av * b4.z;
        acc[ri][3] += av * b4.w;
      }
    }
  }
  // write hs (sorted order, coalesced)
  float4* hs4 = reinterpret_cast<float4*>(hs);
  #pragma unroll
  for (int ri = 0; ri < 4; ++ri) {
    hs4[((size_t)(head * NN + seg * SEG + ty * 4 + ri)) * 32 + tx] =
        make_float4(acc[ri][0], acc[ri][1], acc[ri][2], acc[ri][3]);
  }
  // weighted partial sums over this thread's 4 rows
  #pragma unroll
  for (int c = 0; c < 4; ++c) {
    float p0 = 0.f, p1 = 0.f;
    #pragma unroll
    for (int ri = 0; ri < 4; ++ri) {
      int R = ty * 4 + ri;
      p0 += se0[R] * acc[ri][c];
      p1 += se1[R] * acc[ri][c];
    }
    red[ty * 128 + tx * 4 + c] = p0;
    red[1024 + ty * 128 + tx * 4 + c] = p1;
  }
  __syncthreads();
  if (tid < FF) {
    float a0 = 0.f, a1 = 0.f;
    #pragma unroll
    for (int g = 0; g < 8; ++g) {
      a0 += red[g * 128 + tid];
      a1 += red[1024 + g * 128 + tid];
    }
    size_t base = ((size_t)(head * NSEG + seg)) * 2 * FF;
    segs[base + tid] = a0;
    segs[base + FF + tid] = a1;
  }
  if (tid == 0) {
    float z0 = 0.f, z1 = 0.f;
    #pragma unroll
    for (int j = 0; j < SEG; ++j) { z0 += se0[j]; z1 += se1[j]; }
    segz[(head * NSEG + seg) * 2 + 0] = z0;
    segz[(head * NSEG + seg) * 2 + 1] = z1;
  }
}

// K4: thresholds t(h,n) = #{d <= -s} via 32K independent binary searches.
__global__ __launch_bounds__(256) void k4_thresh(
    const float* __restrict__ attn_src, const float* __restrict__ dsort,
    int* __restrict__ tpos) {
  const int i = blockIdx.x * 256 + threadIdx.x;
  const int head = i >> 12, n = i & (NN - 1);
  const float thr = -attn_src[head * NN + n];
  const float* dp = dsort + head * NN;
  int lo = 0, hi = NN;
  while (lo < hi) {
    int mid = (lo + hi) >> 1;
    if (dp[mid] <= thr) lo = mid + 1; else hi = mid;
  }
  tpos[i] = lo;
}

// kF: inclusive prefix arrays PF[h][j][2][128] + PFz[h][j][2]; hs read LINEAR.
__global__ __launch_bounds__(128) void kF_prefix(
    const float* __restrict__ hs, const float* __restrict__ dsort,
    const float* __restrict__ segs, const float* __restrict__ segz,
    float* __restrict__ PF, float* __restrict__ PFz) {
  __shared__ float se0[SEG], se1[SEG];
  const int head = blockIdx.y, seg = blockIdx.x;
  const int o = threadIdx.x;
  if (o < SEG) {
    float dv = dsort[head * NN + seg * SEG + o];
    se0[o] = expf(0.2f * dv);
    se1[o] = expf(dv);
  }
  __syncthreads();
  float r0 = 0.f, r1 = 0.f, z0 = 0.f, z1 = 0.f;
  const float* sbase = segs + ((size_t)head * NSEG) * 2 * FF;
  #pragma unroll 8
  for (int k = 0; k < seg; ++k) {
    r0 += sbase[(size_t)k * 2 * FF + o];
    r1 += sbase[(size_t)k * 2 * FF + FF + o];
  }
  #pragma unroll 8
  for (int k = 0; k < seg; ++k) {
    z0 += segz[(head * NSEG + k) * 2 + 0];
    z1 += segz[(head * NSEG + k) * 2 + 1];
  }
  const float* hrow = hs + ((size_t)(head * NN + seg * SEG)) * FF + o;
  #pragma unroll 8
  for (int jj = 0; jj < SEG; ++jj) {
    int j = seg * SEG + jj;
    float hv = hrow[(size_t)jj * FF];
    float e0 = se0[jj], e1 = se1[jj];
    r0 += e0 * hv;
    r1 += e1 * hv;
    z0 += e0;
    z1 += e1;
    size_t pb = ((size_t)(head * NN + j)) * 2 * FF;
    PF[pb + o] = r0;
    PF[pb + FF + o] = r1;
    if (o == 0) {
      PFz[(head * NN + j) * 2 + 0] = z0;
      PFz[(head * NN + j) * 2 + 1] = z1;
    }
  }
}

// K6: pure gather/combine using precomputed thresholds; mean over heads + bias.
__global__ __launch_bounds__(128) void k6_out(
    const float* __restrict__ attn_src, const int* __restrict__ tpos,
    const float* __restrict__ PF, const float* __restrict__ PFz,
    const float* __restrict__ bias, float* __restrict__ out) {
  const int n = blockIdx.x, o = threadIdx.x;
  float acc = 0.f;
  #pragma unroll
  for (int head = 0; head < NH; ++head) {
    float s = attn_src[head * NN + n];
    int t = tpos[head * NN + n];
    size_t tb = ((size_t)(head * NN + NN - 1)) * 2 * FF;
    float TotA = PF[tb + FF + o];
    float z1tot = PFz[(head * NN + NN - 1) * 2 + 1];
    float B = 0.f, P1 = 0.f, z0p = 0.f, z1p = 0.f;
    if (t > 0) {
      size_t pb = ((size_t)(head * NN + t - 1)) * 2 * FF;
      B = PF[pb + o];
      P1 = PF[pb + FF + o];
      z0p = PFz[(head * NN + t - 1) * 2 + 0];
      z1p = PFz[(head * NN + t - 1) * 2 + 1];
    }
    float e02s = expf(0.2f * s), es = expf(s);
    float den = e02s * z0p + es * (z1tot - z1p);
    acc += (e02s * B + es * (TotA - P1)) / den;
  }
  out[(size_t)n * FF + o] = 0.125f * acc + bias[o];
}

extern "C" void kernel_launch(void* const* d_in, const int* in_sizes, int n_in,
                              void* d_out, int out_size, void* d_ws,
                              size_t ws_size, hipStream_t stream) {
  const float* h = (const float*)d_in[0];
  const float* w = (const float*)d_in[1];
  const float* a_src = (const float*)d_in[2];
  const float* a_dst = (const float*)d_in[3];
  const float* bias = (const float*)d_in[4];
  float* out = (float*)d_out;

  char* ws = (char*)d_ws;
  size_t off = 0;
  auto alloc = [&](size_t bytes) -> void* {
    void* p = ws + off;
    off += (bytes + 255) & ~(size_t)255;
    return p;
  };
  float* hs = (float*)alloc((size_t)NH * NN * FF * 4);      // 16.8 MB (sorted)
  float* va_s = (float*)alloc((size_t)NH * FF * 4);
  float* va_d = (float*)alloc((size_t)NH * FF * 4);
  float* asrc = (float*)alloc((size_t)NH * NN * 4);
  float* adst = (float*)alloc((size_t)NH * NN * 4);
  float* dsort = (float*)alloc((size_t)NH * NN * 4);
  int* permd = (int*)alloc((size_t)NH * NN * 4);
  int* tpos = (int*)alloc((size_t)NH * NN * 4);
  float* segs = (float*)alloc((size_t)NH * NSEG * 2 * FF * 4);
  float* segz = (float*)alloc((size_t)NH * NSEG * 2 * 4);
  float* PF = (float*)alloc((size_t)NH * NN * 2 * FF * 4);  // 33.5 MB
  float* PFz = (float*)alloc((size_t)NH * NN * 2 * 4);
  u64* sbuf0 = (u64*)alloc((size_t)NH * NN * 8);
  u64* sbuf1 = (u64*)alloc((size_t)NH * NN * 8);
  (void)ws_size; (void)in_sizes; (void)n_in;

  kA_va<<<NH, 128, 0, stream>>>(w, a_src, a_dst, va_s, va_d);
  kB_scores<<<NN / 32, 256, 0, stream>>>(h, va_s, va_d, asrc, adst);
  k2a_localsort<<<dim3(8, NH), 256, 0, stream>>>(adst, sbuf0);
  k2m<512, false><<<dim3(4, NH), 256, 0, stream>>>(sbuf0, sbuf1, nullptr,
                                                   nullptr);
  k2m<1024, false><<<dim3(4, NH), 256, 0, stream>>>(sbuf1, sbuf0, nullptr,
                                                    nullptr);
  k2m<2048, true><<<dim3(4, NH), 256, 0, stream>>>(sbuf0, nullptr, dsort,
                                                   permd);
  kD_gemm_seg<<<dim3(NSEG, NH), 256, 0, stream>>>(h, w, dsort, permd, hs, segs,
                                                  segz);
  k4_thresh<<<NH * NN / 256, 256, 0, stream>>>(asrc, dsort, tpos);
  kF_prefix<<<dim3(NSEG, NH), 128, 0, stream>>>(hs, dsort, segs, segz, PF,
                                                PFz);
  k6_out<<<NN, 128, 0, stream>>>(asrc, tpos, PF, PFz, bias, out);
}

// Round 14
// 159.555 us; speedup vs baseline: 1.0297x; 1.0297x over previous
//
#include <hip/hip_runtime.h>
#include <math.h>

#define NH 8
#define NN 4096
#define FF 128
#define SEG 32
#define NSEG (NN / SEG)  // 128

typedef unsigned long long u64;

// kA: va_src[h] = W_h @ a_src[h], va_dst[h] = W_h @ a_dst[h].  (8 blocks)
__global__ __launch_bounds__(128) void kA_va(
    const float* __restrict__ w, const float* __restrict__ a_src,
    const float* __restrict__ a_dst, float* __restrict__ va_s,
    float* __restrict__ va_d) {
  __shared__ float as[FF], ad[FF];
  const int head = blockIdx.x, i = threadIdx.x;
  as[i] = a_src[head * FF + i];
  ad[i] = a_dst[head * FF + i];
  __syncthreads();
  const float4* wr = reinterpret_cast<const float4*>(w + (size_t)head * FF * FF +
                                                     (size_t)i * FF);
  float s = 0.f, d = 0.f;
  #pragma unroll 8
  for (int q = 0; q < 32; ++q) {
    float4 v = wr[q];
    s += v.x * as[q * 4] + v.y * as[q * 4 + 1] + v.z * as[q * 4 + 2] +
         v.w * as[q * 4 + 3];
    d += v.x * ad[q * 4] + v.y * ad[q * 4 + 1] + v.z * ad[q * 4 + 2] +
         v.w * ad[q * 4 + 3];
  }
  va_s[head * FF + i] = s;
  va_d[head * FF + i] = d;
}

// kB: scores attn_src[h,n] = h[n].va_s[h], attn_dst likewise. 32 rows/block.
__global__ __launch_bounds__(256) void kB_scores(
    const float* __restrict__ h, const float* __restrict__ va_s,
    const float* __restrict__ va_d, float* __restrict__ attn_src,
    float* __restrict__ attn_dst) {
  __shared__ float sh[32 * 132];          // h rows, padded stride
  __shared__ float vs[NH * 132], vd[NH * 132];
  const int r0 = blockIdx.x * 32;
  const int tid = threadIdx.x;
  const float4* hg = reinterpret_cast<const float4*>(h);
  #pragma unroll
  for (int it = 0; it < 4; ++it) {
    int q = tid + it * 256;
    int row = q >> 5, c4 = q & 31;
    float4 v = hg[(size_t)(r0 + row) * 32 + c4];
    float* dst = &sh[row * 132 + c4 * 4];
    dst[0] = v.x; dst[1] = v.y; dst[2] = v.z; dst[3] = v.w;
  }
  for (int q = tid; q < NH * FF; q += 256) {
    int hd = q >> 7, k = q & 127;
    vs[hd * 132 + k] = va_s[q];
    vd[hd * 132 + k] = va_d[q];
  }
  __syncthreads();
  const int row = tid >> 3, head = tid & 7;
  float s = 0.f, d = 0.f;
  const float* hr = &sh[row * 132];
  const float* vsp = &vs[head * 132];
  const float* vdp = &vd[head * 132];
  #pragma unroll 8
  for (int k = 0; k < FF; ++k) {
    float hv = hr[k];
    s += hv * vsp[k];
    d += hv * vdp[k];
  }
  attn_src[head * NN + r0 + row] = s;
  attn_dst[head * NN + r0 + row] = d;
}

// K2a: per (head, 512-chunk): bitonic sort of packed (sortkey32|idx) in LDS.
__global__ __launch_bounds__(256) void k2a_localsort(
    const float* __restrict__ adst, u64* __restrict__ runs) {
  __shared__ u64 sk[512];
  const int head = blockIdx.y, chunk = blockIdx.x, tid = threadIdx.x;
  const int base = head * NN + chunk * 512;
  for (int i = tid; i < 512; i += 256) {
    unsigned ub = __float_as_uint(adst[base + i]);
    unsigned u = (ub & 0x80000000u) ? ~ub : (ub | 0x80000000u);
    sk[i] = ((u64)u << 32) | (unsigned)(chunk * 512 + i);
  }
  __syncthreads();
  for (int k = 2; k <= 512; k <<= 1) {
    for (int j = k >> 1; j > 0; j >>= 1) {
      for (int t = tid; t < 512; t += 256) {
        int ixj = t ^ j;
        if (ixj > t) {
          u64 a = sk[t], b = sk[ixj];
          bool up = ((t & k) == 0);
          if (up ? (a > b) : (a < b)) { sk[t] = b; sk[ixj] = a; }
        }
      }
      __syncthreads();
    }
  }
  for (int i = tid; i < 512; i += 256) runs[base + i] = sk[i];
}

// K2b: per (head, 2048-half): two LDS merge-path levels 512->1024->2048.
__global__ __launch_bounds__(256) void k2b_localmerge(
    const u64* __restrict__ src, u64* __restrict__ dst) {
  __shared__ u64 b0[2048], b1[2048];
  const int head = blockIdx.y, half = blockIdx.x, tid = threadIdx.x;
  const int base = head * NN + half * 2048;
  for (int i = tid; i < 2048; i += 256) b0[i] = src[base + i];
  __syncthreads();
  {  // level 1: L=512, regions of 1024
    const int q = tid * 8;
    const int region = q >> 10, q0 = q & 1023;
    const u64* A = &b0[region << 10];
    const u64* B = A + 512;
    int lo = q0 > 512 ? q0 - 512 : 0, hi = q0 < 512 ? q0 : 512;
    while (lo < hi) {
      int mid = (lo + hi) >> 1;
      if (A[mid] < B[q0 - 1 - mid]) lo = mid + 1; else hi = mid;
    }
    int a = lo, b = q0 - lo;
    #pragma unroll
    for (int t = 0; t < 8; ++t) {
      u64 va = a < 512 ? A[a] : ~0ULL;
      u64 vb = b < 512 ? B[b] : ~0ULL;
      u64 v;
      if (va < vb) { v = va; ++a; } else { v = vb; ++b; }
      b1[(region << 10) + q0 + t] = v;
    }
  }
  __syncthreads();
  {  // level 2: L=1024, single region of 2048
    const int q0 = tid * 8;
    const u64* A = b1;
    const u64* B = b1 + 1024;
    int lo = q0 > 1024 ? q0 - 1024 : 0, hi = q0 < 1024 ? q0 : 1024;
    while (lo < hi) {
      int mid = (lo + hi) >> 1;
      if (A[mid] < B[q0 - 1 - mid]) lo = mid + 1; else hi = mid;
    }
    int a = lo, b = q0 - lo;
    #pragma unroll
    for (int t = 0; t < 8; ++t) {
      u64 va = a < 1024 ? A[a] : ~0ULL;
      u64 vb = b < 1024 ? B[b] : ~0ULL;
      u64 v;
      if (va < vb) { v = va; ++a; } else { v = vb; ++b; }
      b0[q0 + t] = v;
    }
  }
  __syncthreads();
  for (int i = tid; i < 2048; i += 256) dst[base + i] = b0[i];
}

// K2m: final merge-path merge of two 2048-runs; unpack to dsort/permd.
__global__ __launch_bounds__(256) void k2m_final(
    const u64* __restrict__ src, float* __restrict__ dsort,
    int* __restrict__ permd) {
  const int L = 2048;
  const int head = blockIdx.y;
  const int i = (blockIdx.x * 256 + threadIdx.x) * 4;
  const u64* S = src + head * NN;
  const int q0 = i;  // single region (2L == NN)
  const u64* A = S;
  const u64* B = S + L;
  int lo = q0 > L ? q0 - L : 0, hi = q0 < L ? q0 : L;
  while (lo < hi) {
    int mid = (lo + hi) >> 1;
    if (A[mid] < B[q0 - 1 - mid]) lo = mid + 1; else hi = mid;
  }
  int a = lo, b = q0 - lo;
  #pragma unroll
  for (int t = 0; t < 4; ++t) {
    u64 va = a < L ? A[a] : ~0ULL;
    u64 vb = b < L ? B[b] : ~0ULL;
    u64 v;
    if (va < vb) { v = va; ++a; } else { v = vb; ++b; }
    const int q = q0 + t;
    unsigned u = (unsigned)(v >> 32);
    unsigned ub = (u & 0x80000000u) ? (u ^ 0x80000000u) : ~u;
    dsort[head * NN + q] = __uint_as_float(ub);
    permd[head * NN + q] = (int)(v & 0xffffffffu);
  }
}

// kD: per (head, 32-row sorted tile): gather h[perm] rows (L2-resident),
// GEMM vs W_h (LDS chunk-staged), write hs in SORTED order (linear),
// and emit segment sums of e^{0.2d}.h' / e^{d}.h' + scalar z sums.
__global__ __launch_bounds__(256) void kD_gemm_seg(
    const float* __restrict__ h, const float* __restrict__ w,
    const float* __restrict__ dsort, const int* __restrict__ permd,
    float* __restrict__ hs, float* __restrict__ segs,
    float* __restrict__ segz) {
  __shared__ float sw[32 * 128];   // W k-chunk [32 k][128 o]
  __shared__ float hA[32 * 128];   // gathered h rows [row][k]
  __shared__ float red[2 * 8 * 128];
  __shared__ float se0[SEG], se1[SEG];
  __shared__ int sp[SEG];
  const int head = blockIdx.y, seg = blockIdx.x;
  const int tid = threadIdx.x;
  const int ty = tid >> 5, tx = tid & 31;
  if (tid < SEG) {
    float dv = dsort[head * NN + seg * SEG + tid];
    se0[tid] = expf(0.2f * dv);
    se1[tid] = expf(dv);
    sp[tid] = permd[head * NN + seg * SEG + tid];
  }
  __syncthreads();
  // gather 32 h rows into hA
  const float4* hg = reinterpret_cast<const float4*>(h);
  #pragma unroll
  for (int it = 0; it < 4; ++it) {
    int row = tid >> 3, c4 = (tid & 7) + it * 8;
    float4 v = hg[(size_t)sp[row] * 32 + c4];
    float* dst = &hA[row * 128 + c4 * 4];
    dst[0] = v.x; dst[1] = v.y; dst[2] = v.z; dst[3] = v.w;
  }
  float acc[4][4];
  #pragma unroll
  for (int i = 0; i < 4; ++i)
    #pragma unroll
    for (int j = 0; j < 4; ++j) acc[i][j] = 0.f;
  const float4* wg = reinterpret_cast<const float4*>(w + (size_t)head * FF * FF);
  for (int kc = 0; kc < 4; ++kc) {
    const int k0 = kc * 32;
    __syncthreads();
    #pragma unroll
    for (int it = 0; it < 4; ++it) {
      int q = tid + it * 256;
      int krow = q >> 5, c4 = q & 31;
      float4 v = wg[(size_t)(k0 + krow) * 32 + c4];
      float* dst = &sw[krow * 128 + c4 * 4];
      dst[0] = v.x; dst[1] = v.y; dst[2] = v.z; dst[3] = v.w;
    }
    __syncthreads();
    #pragma unroll 8
    for (int kk = 0; kk < 32; ++kk) {
      float4 b4 = *reinterpret_cast<const float4*>(&sw[kk * 128 + tx * 4]);
      #pragma unroll
      for (int ri = 0; ri < 4; ++ri) {
        float av = hA[(ty * 4 + ri) * 128 + k0 + kk];
        acc[ri][0] += av * b4.x;
        acc[ri][1] += av * b4.y;
        acc[ri][2] += av * b4.z;
        acc[ri][3] += av * b4.w;
      }
    }
  }
  // write hs (sorted order, coalesced)
  float4* hs4 = reinterpret_cast<float4*>(hs);
  #pragma unroll
  for (int ri = 0; ri < 4; ++ri) {
    hs4[((size_t)(head * NN + seg * SEG + ty * 4 + ri)) * 32 + tx] =
        make_float4(acc[ri][0], acc[ri][1], acc[ri][2], acc[ri][3]);
  }
  // weighted partial sums over this thread's 4 rows
  #pragma unroll
  for (int c = 0; c < 4; ++c) {
    float p0 = 0.f, p1 = 0.f;
    #pragma unroll
    for (int ri = 0; ri < 4; ++ri) {
      int R = ty * 4 + ri;
      p0 += se0[R] * acc[ri][c];
      p1 += se1[R] * acc[ri][c];
    }
    red[ty * 128 + tx * 4 + c] = p0;
    red[1024 + ty * 128 + tx * 4 + c] = p1;
  }
  __syncthreads();
  if (tid < FF) {
    float a0 = 0.f, a1 = 0.f;
    #pragma unroll
    for (int g = 0; g < 8; ++g) {
      a0 += red[g * 128 + tid];
      a1 += red[1024 + g * 128 + tid];
    }
    size_t base = ((size_t)(head * NSEG + seg)) * 2 * FF;
    segs[base + tid] = a0;
    segs[base + FF + tid] = a1;
  }
  if (tid == 0) {
    float z0 = 0.f, z1 = 0.f;
    #pragma unroll
    for (int j = 0; j < SEG; ++j) { z0 += se0[j]; z1 += se1[j]; }
    segz[(head * NSEG + seg) * 2 + 0] = z0;
    segz[(head * NSEG + seg) * 2 + 1] = z1;
  }
}

// kF: inclusive prefix arrays PF[h][j][2][128] + PFz[h][j][2]; hs read LINEAR.
__global__ __launch_bounds__(128) void kF_prefix(
    const float* __restrict__ hs, const float* __restrict__ dsort,
    const float* __restrict__ segs, const float* __restrict__ segz,
    float* __restrict__ PF, float* __restrict__ PFz) {
  __shared__ float se0[SEG], se1[SEG];
  const int head = blockIdx.y, seg = blockIdx.x;
  const int o = threadIdx.x;
  if (o < SEG) {
    float dv = dsort[head * NN + seg * SEG + o];
    se0[o] = expf(0.2f * dv);
    se1[o] = expf(dv);
  }
  __syncthreads();
  float r0 = 0.f, r1 = 0.f, z0 = 0.f, z1 = 0.f;
  const float* sbase = segs + ((size_t)head * NSEG) * 2 * FF;
  #pragma unroll 8
  for (int k = 0; k < seg; ++k) {
    r0 += sbase[(size_t)k * 2 * FF + o];
    r1 += sbase[(size_t)k * 2 * FF + FF + o];
  }
  #pragma unroll 8
  for (int k = 0; k < seg; ++k) {
    z0 += segz[(head * NSEG + k) * 2 + 0];
    z1 += segz[(head * NSEG + k) * 2 + 1];
  }
  const float* hrow = hs + ((size_t)(head * NN + seg * SEG)) * FF + o;
  #pragma unroll 8
  for (int jj = 0; jj < SEG; ++jj) {
    int j = seg * SEG + jj;
    float hv = hrow[(size_t)jj * FF];
    float e0 = se0[jj], e1 = se1[jj];
    r0 += e0 * hv;
    r1 += e1 * hv;
    z0 += e0;
    z1 += e1;
    size_t pb = ((size_t)(head * NN + j)) * 2 * FF;
    PF[pb + o] = r0;
    PF[pb + FF + o] = r1;
    if (o == 0) {
      PFz[(head * NN + j) * 2 + 0] = z0;
      PFz[(head * NN + j) * 2 + 1] = z1;
    }
  }
}

// K6: 8 parallel binary searches (thread per head) + per-head combine.
__global__ __launch_bounds__(128) void k6_out(
    const float* __restrict__ attn_src, const float* __restrict__ dsort,
    const float* __restrict__ PF, const float* __restrict__ PFz,
    const float* __restrict__ bias, float* __restrict__ out) {
  __shared__ int st[NH];
  __shared__ float ss[NH];
  const int n = blockIdx.x, o = threadIdx.x;
  if (o < NH) {
    float s = attn_src[o * NN + n];
    ss[o] = s;
    const float* dp = dsort + o * NN;
    float thr = -s;
    int lo = 0, hi = NN;
    while (lo < hi) {
      int mid = (lo + hi) >> 1;
      if (dp[mid] <= thr) lo = mid + 1; else hi = mid;
    }
    st[o] = lo;  // t = #{d <= -s}: these take the 0.2-slope branch
  }
  __syncthreads();
  float acc = 0.f;
  #pragma unroll
  for (int head = 0; head < NH; ++head) {
    float s = ss[head];
    int t = st[head];
    size_t tb = ((size_t)(head * NN + NN - 1)) * 2 * FF;
    float TotA = PF[tb + FF + o];
    float z1tot = PFz[(head * NN + NN - 1) * 2 + 1];
    float B = 0.f, P1 = 0.f, z0p = 0.f, z1p = 0.f;
    if (t > 0) {
      size_t pb = ((size_t)(head * NN + t - 1)) * 2 * FF;
      B = PF[pb + o];
      P1 = PF[pb + FF + o];
      z0p = PFz[(head * NN + t - 1) * 2 + 0];
      z1p = PFz[(head * NN + t - 1) * 2 + 1];
    }
    float e02s = expf(0.2f * s), es = expf(s);
    float den = e02s * z0p + es * (z1tot - z1p);
    acc += (e02s * B + es * (TotA - P1)) / den;
  }
  out[(size_t)n * FF + o] = 0.125f * acc + bias[o];
}

extern "C" void kernel_launch(void* const* d_in, const int* in_sizes, int n_in,
                              void* d_out, int out_size, void* d_ws,
                              size_t ws_size, hipStream_t stream) {
  const float* h = (const float*)d_in[0];
  const float* w = (const float*)d_in[1];
  const float* a_src = (const float*)d_in[2];
  const float* a_dst = (const float*)d_in[3];
  const float* bias = (const float*)d_in[4];
  float* out = (float*)d_out;

  char* ws = (char*)d_ws;
  size_t off = 0;
  auto alloc = [&](size_t bytes) -> void* {
    void* p = ws + off;
    off += (bytes + 255) & ~(size_t)255;
    return p;
  };
  float* hs = (float*)alloc((size_t)NH * NN * FF * 4);      // 16.8 MB (sorted)
  float* va_s = (float*)alloc((size_t)NH * FF * 4);
  float* va_d = (float*)alloc((size_t)NH * FF * 4);
  float* asrc = (float*)alloc((size_t)NH * NN * 4);
  float* adst = (float*)alloc((size_t)NH * NN * 4);
  float* dsort = (float*)alloc((size_t)NH * NN * 4);
  int* permd = (int*)alloc((size_t)NH * NN * 4);
  float* segs = (float*)alloc((size_t)NH * NSEG * 2 * FF * 4);
  float* segz = (float*)alloc((size_t)NH * NSEG * 2 * 4);
  float* PF = (float*)alloc((size_t)NH * NN * 2 * FF * 4);  // 33.5 MB
  float* PFz = (float*)alloc((size_t)NH * NN * 2 * 4);
  u64* sbuf0 = (u64*)alloc((size_t)NH * NN * 8);
  u64* sbuf1 = (u64*)alloc((size_t)NH * NN * 8);
  (void)ws_size; (void)in_sizes; (void)n_in;

  kA_va<<<NH, 128, 0, stream>>>(w, a_src, a_dst, va_s, va_d);
  kB_scores<<<NN / 32, 256, 0, stream>>>(h, va_s, va_d, asrc, adst);
  k2a_localsort<<<dim3(8, NH), 256, 0, stream>>>(adst, sbuf0);
  k2b_localmerge<<<dim3(2, NH), 256, 0, stream>>>(sbuf0, sbuf1);
  k2m_final<<<dim3(4, NH), 256, 0, stream>>>(sbuf1, dsort, permd);
  kD_gemm_seg<<<dim3(NSEG, NH), 256, 0, stream>>>(h, w, dsort, permd, hs, segs,
                                                  segz);
  kF_prefix<<<dim3(NSEG, NH), 128, 0, stream>>>(hs, dsort, segs, segz, PF,
                                                PFz);
  k6_out<<<NN, 128, 0, stream>>>(asrc, dsort, PF, PFz, bias, out);
}